// Round 2
// baseline (1597.966 us; speedup 1.0000x reference)
//
#include <hip/hip_runtime.h>

#define EPS 1e-6f

// DPP helper: v += v rotated by CTRL within each 16-lane row (row_ror:n = 0x120+n)
template <int CTRL>
__device__ __forceinline__ float dpp_add(float v) {
  int moved = __builtin_amdgcn_update_dpp(0, __float_as_int(v), CTRL, 0xF, 0xF, false);
  return v + __int_as_float(moved);
}

// ---------------------------------------------------------------------------
// Kernel A: Ppart[h][b][n][r] = sum_{d in half h} x[b,n,d] * bases[b,d,r]
// grid (32 grp, 16 b, 2 h) = 1024 blocks; block 256 = 4 waves.
// NO LDS, NO barriers: bases (4 MB total) is L2-resident; each lane loads its
// own bases rows as float4 straight from global. Round-1 post-mortem showed
// the barrier-serialized LDS pipeline left every pipe at ~20% -- streaming
// with free-slipping waves instead. Lane owns 4 contiguous d (x = dwordx4,
// 1-deep prefetch); wave owns 4 n-rows x 16 r (acc[4][16] = 64 VGPR).
// Blocks (grp==0, h==0) also zero CtC for this iteration's fused coef-gram.
// ---------------------------------------------------------------------------
__global__ __launch_bounds__(256, 4) void kernelA(
    const float* __restrict__ x, const float* __restrict__ bases,
    float* __restrict__ Ppart, float* __restrict__ CtC)
{
  const int tid = threadIdx.x;
  const int grp = blockIdx.x;
  const int b = blockIdx.y;
  const int h = blockIdx.z;
  if (h == 0 && grp == 0) CtC[b * 256 + tid] = 0.0f;
  const int w = tid >> 6;
  const int lane = tid & 63;
  const int n0 = grp * 16 + w * 4;
  const float* __restrict__ xp =
      x + ((size_t)(b * 512 + n0)) * 4096 + h * 2048 + lane * 4;
  const float4* __restrict__ bp =
      (const float4*)(bases + ((size_t)(b * 4096 + h * 2048 + lane * 4)) * 16);

  float acc[4][16];
#pragma unroll
  for (int i = 0; i < 4; ++i)
#pragma unroll
    for (int r = 0; r < 16; ++r) acc[i][r] = 0.0f;

  // prefetch j=0 x
  float4 xv[4], xn[4];
#pragma unroll
  for (int i = 0; i < 4; ++i) xv[i] = *(const float4*)(xp + (size_t)i * 4096);

  for (int j = 0; j < 8; ++j) {
    if (j < 7) {
#pragma unroll
      for (int i = 0; i < 4; ++i)
        xn[i] = *(const float4*)(xp + (size_t)i * 4096 + (size_t)(j + 1) * 256);
    }
#pragma unroll
    for (int k = 0; k < 4; ++k) {
      // bases row d = j*256 + lane*4 + k : 16 r values = 4 float4 (L2-hit)
      const float4* __restrict__ brow = bp + (size_t)(j * 256 + k) * 4;
      float4 bq0 = brow[0];
      float4 bq1 = brow[1];
      float4 bq2 = brow[2];
      float4 bq3 = brow[3];
#pragma unroll
      for (int i = 0; i < 4; ++i) {
        const float xf = (&xv[i].x)[k];
        acc[i][0]  = fmaf(xf, bq0.x, acc[i][0]);
        acc[i][1]  = fmaf(xf, bq0.y, acc[i][1]);
        acc[i][2]  = fmaf(xf, bq0.z, acc[i][2]);
        acc[i][3]  = fmaf(xf, bq0.w, acc[i][3]);
        acc[i][4]  = fmaf(xf, bq1.x, acc[i][4]);
        acc[i][5]  = fmaf(xf, bq1.y, acc[i][5]);
        acc[i][6]  = fmaf(xf, bq1.z, acc[i][6]);
        acc[i][7]  = fmaf(xf, bq1.w, acc[i][7]);
        acc[i][8]  = fmaf(xf, bq2.x, acc[i][8]);
        acc[i][9]  = fmaf(xf, bq2.y, acc[i][9]);
        acc[i][10] = fmaf(xf, bq2.z, acc[i][10]);
        acc[i][11] = fmaf(xf, bq2.w, acc[i][11]);
        acc[i][12] = fmaf(xf, bq3.x, acc[i][12]);
        acc[i][13] = fmaf(xf, bq3.y, acc[i][13]);
        acc[i][14] = fmaf(xf, bq3.z, acc[i][14]);
        acc[i][15] = fmaf(xf, bq3.w, acc[i][15]);
      }
    }
#pragma unroll
    for (int i = 0; i < 4; ++i) xv[i] = xn[i];
  }

  // butterfly-reduce each acc over the 64 lanes (all lanes end with the sum)
#pragma unroll
  for (int i = 0; i < 4; ++i)
#pragma unroll
    for (int r = 0; r < 16; ++r) {
      float v = acc[i][r];
      v = dpp_add<0x121>(v);
      v = dpp_add<0x122>(v);
      v = dpp_add<0x124>(v);
      v = dpp_add<0x128>(v);
      v += __shfl_xor(v, 16, 64);
      v += __shfl_xor(v, 32, 64);
      acc[i][r] = v;
    }

  if (lane == 0) {
    float* __restrict__ pp =
        Ppart + (((size_t)(h * 16 + b)) * 512 + n0) * 16;
#pragma unroll
    for (int i = 0; i < 4; ++i) {
#pragma unroll
      for (int q = 0; q < 4; ++q)
        *(float4*)(pp + i * 16 + q * 4) =
            make_float4(acc[i][q * 4], acc[i][q * 4 + 1], acc[i][q * 4 + 2], acc[i][q * 4 + 3]);
    }
  }
}

// ---------------------------------------------------------------------------
// Softmax init: coef[b,n,:] = softmax(100 * (Ppart0 + Ppart1)[b,n,:])
// grid 32 x 256; thread = one n row.
// ---------------------------------------------------------------------------
__global__ __launch_bounds__(256) void kernelSM(
    const float* __restrict__ Ppart, float* __restrict__ coef)
{
  const int gid = blockIdx.x * 256 + threadIdx.x;  // 0..8191
  const int b = gid >> 9, n = gid & 511;
  const float* __restrict__ p0 = Ppart + (((size_t)b) * 512 + n) * 16;
  const float* __restrict__ p1 = Ppart + (((size_t)(16 + b)) * 512 + n) * 16;
  float p[16];
#pragma unroll
  for (int r = 0; r < 16; ++r) p[r] = p0[r] + p1[r];
  float m = p[0];
#pragma unroll
  for (int r = 1; r < 16; ++r) m = fmaxf(m, p[r]);
  float e[16];
  float s = 0.0f;
#pragma unroll
  for (int r = 0; r < 16; ++r) { e[r] = __expf(100.0f * (p[r] - m)); s += e[r]; }
  float inv = 1.0f / s;
  float* __restrict__ crow = coef + (((size_t)b) * 512 + n) * 16;
#pragma unroll
  for (int r = 0; r < 16; ++r) crow[r] = e[r] * inv;
}

// ---------------------------------------------------------------------------
// Standalone gram (used once for BtB0): out[b,s*16+r] += sum_l M[.,r]*M[.,s]
// ---------------------------------------------------------------------------
__global__ __launch_bounds__(256) void kernelGram(
    const float* __restrict__ M, float* __restrict__ out, int L)
{
  __shared__ __align__(16) float sm[256 * 20];
  __shared__ __align__(16) float part[4 * 272];
  const int tid = threadIdx.x;
  const int b = blockIdx.y;
  const int sl = blockIdx.x;
  const float4* __restrict__ src = (const float4*)(M + ((size_t)b * L + (size_t)sl * 256) * 16);
#pragma unroll
  for (int k = 0; k < 4; ++k) {
    int idx = k * 256 + tid;
    int row = idx >> 2, q = idx & 3;
    *(float4*)(&sm[row * 20 + q * 4]) = src[idx];
  }
  __syncthreads();
  const int rq = tid & 3;
  const int s = (tid >> 2) & 15;
  const int g = tid >> 6;
  float a0 = 0.f, a1 = 0.f, a2 = 0.f, a3 = 0.f;
#pragma unroll 4
  for (int l = g * 64; l < g * 64 + 64; ++l) {
    float4 bv = *(const float4*)(&sm[l * 20 + rq * 4]);
    float cs = sm[l * 20 + s];
    a0 = fmaf(cs, bv.x, a0);
    a1 = fmaf(cs, bv.y, a1);
    a2 = fmaf(cs, bv.z, a2);
    a3 = fmaf(cs, bv.w, a3);
  }
  *(float4*)(&part[g * 272 + s * 16 + rq * 4]) = make_float4(a0, a1, a2, a3);
  __syncthreads();
  float v = part[0 * 272 + tid] + part[1 * 272 + tid] + part[2 * 272 + tid] + part[3 * 272 + tid];
  atomicAdd(out + b * 256 + tid, v);
}

// ---------------------------------------------------------------------------
// Coef update + fused CtC gram: coef *= (P0+P1) / (coef BtB + eps); CtC += gram
// grid 32; block 256 (thread = one n row). Also zeros BtBz.
// ---------------------------------------------------------------------------
__global__ __launch_bounds__(256) void kernelCU(
    float* __restrict__ coef, const float* __restrict__ Ppart,
    const float* __restrict__ BtBr, float* __restrict__ BtBz,
    float* __restrict__ CtCadd)
{
  __shared__ __align__(16) float sm[256 * 20 + 4 * 272];
  const int tid = threadIdx.x;
  BtBz[blockIdx.x * 128 + (tid & 127)] = 0.0f;
  const int b = blockIdx.x >> 1;
  const int n = ((blockIdx.x & 1) << 8) + tid;
  float* __restrict__ crow = coef + ((size_t)(b * 512 + n)) * 16;
  const float* __restrict__ p0 = Ppart + (((size_t)b) * 512 + n) * 16;
  const float* __restrict__ p1 = Ppart + (((size_t)(16 + b)) * 512 + n) * 16;
  const float* __restrict__ btb = BtBr + b * 256;
  float cv[16], den[16];
#pragma unroll
  for (int r = 0; r < 16; ++r) cv[r] = crow[r];
#pragma unroll
  for (int r = 0; r < 16; ++r) den[r] = 0.f;
#pragma unroll
  for (int s2 = 0; s2 < 16; ++s2) {
    const float bs = cv[s2];
#pragma unroll
    for (int r = 0; r < 16; ++r) den[r] = fmaf(bs, btb[s2 * 16 + r], den[r]);
  }
#pragma unroll
  for (int r = 0; r < 16; ++r) {
    float cn = cv[r] * (p0[r] + p1[r]) / (den[r] + EPS);
    crow[r] = cn;
    sm[tid * 20 + r] = cn;
  }
  __syncthreads();
  const int rq = tid & 3;
  const int s = (tid >> 2) & 15;
  const int g = tid >> 6;
  float a0 = 0.f, a1 = 0.f, a2 = 0.f, a3 = 0.f;
#pragma unroll 4
  for (int l = g * 64; l < g * 64 + 64; ++l) {
    float4 bv = *(const float4*)(&sm[l * 20 + rq * 4]);
    float cs = sm[l * 20 + s];
    a0 = fmaf(cs, bv.x, a0);
    a1 = fmaf(cs, bv.y, a1);
    a2 = fmaf(cs, bv.z, a2);
    a3 = fmaf(cs, bv.w, a3);
  }
  float* part = sm + 5120;
  *(float4*)(&part[g * 272 + s * 16 + rq * 4]) = make_float4(a0, a1, a2, a3);
  __syncthreads();
  float v = part[0 * 272 + tid] + part[1 * 272 + tid] + part[2 * 272 + tid] + part[3 * 272 + tid];
  atomicAdd(CtCadd + b * 256 + tid, v);
}

// ---------------------------------------------------------------------------
// Kernel B accumulate: qpart[ns][b][d][r] = sum_{n in slice} x[b,n,d]*coef[b,n,r]
// grid (16 d-tiles, 4 n-slices, 16 b) = 1024 blocks. (Round-0 form: the
// dwordx2/512-block variant of round 1 halved occupancy and cost ~30 us.)
// ---------------------------------------------------------------------------
__global__ __launch_bounds__(256) void kernelBacc(
    const float* __restrict__ x, const float* __restrict__ coef,
    float* __restrict__ qpart)
{
  const int tid = threadIdx.x;
  const int dt = blockIdx.x, ns = blockIdx.y, b = blockIdx.z;
  const int d = dt * 256 + tid;
  const float* __restrict__ xp = x + ((size_t)(b * 512 + ns * 128)) * 4096 + d;
  const float* __restrict__ cp = coef + ((size_t)(b * 512 + ns * 128)) * 16;
  float acc[16];
#pragma unroll
  for (int r = 0; r < 16; ++r) acc[r] = 0.f;
#pragma unroll 4
  for (int n = 0; n < 128; ++n) {
    const float xv = xp[(size_t)n * 4096];
    const float* __restrict__ crow = cp + n * 16;   // wave-uniform -> s_load
#pragma unroll
    for (int r = 0; r < 16; ++r) acc[r] = fmaf(xv, crow[r], acc[r]);
  }
  float* __restrict__ qp = qpart + (((size_t)(ns * 16 + b)) * 4096 + d) * 16;
#pragma unroll
  for (int q = 0; q < 4; ++q)
    *(float4*)(qp + q * 4) = make_float4(acc[q * 4], acc[q * 4 + 1], acc[q * 4 + 2], acc[q * 4 + 3]);
}

// ---------------------------------------------------------------------------
// Kernel B finalize + fused BtB gram.
// grid (16 d-tiles, 16 b); block 256 (thread = one d).
// ---------------------------------------------------------------------------
__global__ __launch_bounds__(256) void kernelBfin(
    const float* __restrict__ qpart, float* __restrict__ bases,
    const float* __restrict__ CtC, float* __restrict__ BtBadd)
{
  __shared__ __align__(16) float sm[256 * 20 + 4 * 272];
  const int tid = threadIdx.x;
  const int dt = blockIdx.x, b = blockIdx.y;
  const int d = dt * 256 + tid;
  float acc[16];
#pragma unroll
  for (int r = 0; r < 16; ++r) acc[r] = 0.f;
#pragma unroll
  for (int ns = 0; ns < 4; ++ns) {
    const float* __restrict__ qp = qpart + (((size_t)(ns * 16 + b)) * 4096 + d) * 16;
#pragma unroll
    for (int q = 0; q < 4; ++q) {
      float4 v = *(const float4*)(qp + q * 4);
      acc[q * 4 + 0] += v.x; acc[q * 4 + 1] += v.y; acc[q * 4 + 2] += v.z; acc[q * 4 + 3] += v.w;
    }
  }
  float* __restrict__ brow = bases + ((size_t)(b * 4096 + d)) * 16;
  float bv[16];
#pragma unroll
  for (int r = 0; r < 16; ++r) bv[r] = brow[r];
  const float* __restrict__ ctc = CtC + b * 256;
  float den[16];
#pragma unroll
  for (int r = 0; r < 16; ++r) den[r] = 0.f;
#pragma unroll
  for (int s2 = 0; s2 < 16; ++s2) {
    const float bs = bv[s2];
#pragma unroll
    for (int r = 0; r < 16; ++r) den[r] = fmaf(bs, ctc[s2 * 16 + r], den[r]);
  }
#pragma unroll
  for (int r = 0; r < 16; ++r) {
    float bn = bv[r] * acc[r] / (den[r] + EPS);
    brow[r] = bn;
    sm[tid * 20 + r] = bn;
  }
  __syncthreads();
  const int rq = tid & 3;
  const int s = (tid >> 2) & 15;
  const int g = tid >> 6;
  float a0 = 0.f, a1 = 0.f, a2 = 0.f, a3 = 0.f;
#pragma unroll 4
  for (int l = g * 64; l < g * 64 + 64; ++l) {
    float4 bq = *(const float4*)(&sm[l * 20 + rq * 4]);
    float cs = sm[l * 20 + s];
    a0 = fmaf(cs, bq.x, a0);
    a1 = fmaf(cs, bq.y, a1);
    a2 = fmaf(cs, bq.z, a2);
    a3 = fmaf(cs, bq.w, a3);
  }
  float* part = sm + 5120;
  *(float4*)(&part[g * 272 + s * 16 + rq * 4]) = make_float4(a0, a1, a2, a3);
  __syncthreads();
  float v = part[0 * 272 + tid] + part[1 * 272 + tid] + part[2 * 272 + tid] + part[3 * 272 + tid];
  atomicAdd(BtBadd + b * 256 + tid, v);
}

// ---------------------------------------------------------------------------
// Output: out[b,n,d] = sum_r bases[b,d,r]*coef[b,n,r]
// grid (4 d-tiles, 16 n-slices, 16 b); thread owns 4 d (float4 stores).
// ---------------------------------------------------------------------------
__global__ __launch_bounds__(256) void kernelOut(
    const float* __restrict__ bases, const float* __restrict__ coef,
    float* __restrict__ out)
{
  const int tid = threadIdx.x;
  const int dt = blockIdx.x, ns = blockIdx.y, b = blockIdx.z;
  const int d0 = dt * 1024 + tid * 4;
  float bv[4][16];
#pragma unroll
  for (int k = 0; k < 4; ++k) {
    const float* __restrict__ brow = bases + ((size_t)(b * 4096 + d0 + k)) * 16;
#pragma unroll
    for (int r = 0; r < 16; ++r) bv[k][r] = brow[r];
  }
  const float* __restrict__ cp = coef + ((size_t)(b * 512 + ns * 32)) * 16;
  float* __restrict__ op = out + ((size_t)(b * 512 + ns * 32)) * 4096 + d0;
#pragma unroll 4
  for (int n = 0; n < 32; ++n) {
    const float* __restrict__ crow = cp + n * 16;
    float v[4];
#pragma unroll
    for (int k = 0; k < 4; ++k) {
      float s = 0.f;
#pragma unroll
      for (int r = 0; r < 16; ++r) s = fmaf(bv[k][r], crow[r], s);
      v[k] = s;
    }
    *(float4*)(op + (size_t)n * 4096) = make_float4(v[0], v[1], v[2], v[3]);
  }
}

// ---------------------------------------------------------------------------
extern "C" void kernel_launch(void* const* d_in, const int* in_sizes, int n_in,
                              void* d_out, int out_size, void* d_ws, size_t ws_size,
                              hipStream_t stream) {
  const float* x = (const float*)d_in[0];         // 16*512*4096
  const float* bases_in = (const float*)d_in[1];  // 16*4096*16
  float* out = (float*)d_out;
  float* ws = (float*)d_ws;

  float* bases = ws;               // 1,048,576 floats
  float* coef  = bases + 1048576;  // 131,072
  float* Ppart = coef + 131072;    // 262,144 (2 d-half partials)
  float* btb0  = Ppart + 262144;   // 4,096
  float* btb1  = btb0 + 4096;      // 4,096
  float* ctc   = btb1 + 4096;      // 4,096
  float* qpart = ctc + 4096;       // 4*16*4096*16 = 4,194,304
  float* btb[2] = {btb0, btb1};

  hipMemsetAsync(btb0, 0, 4096 * sizeof(float), stream);
  hipMemcpyAsync(bases, bases_in, 1048576 * sizeof(float),
                 hipMemcpyDeviceToDevice, stream);

  // init: Ppart = X^T B0 (+ctc zero), coef = softmax(100*P); BtB0 = gram(B0)
  kernelA<<<dim3(32, 16, 2), 256, 0, stream>>>(x, bases, Ppart, ctc);
  kernelSM<<<32, 256, 0, stream>>>(Ppart, coef);
  kernelGram<<<dim3(16, 16), 256, 0, stream>>>(bases, btb0, 4096);

  for (int t = 0; t < 7; ++t) {
    if (t > 0) kernelA<<<dim3(32, 16, 2), 256, 0, stream>>>(x, bases, Ppart, ctc);
    kernelCU<<<32, 256, 0, stream>>>(coef, Ppart, btb[t & 1], btb[(t + 1) & 1], ctc);
    kernelBacc<<<dim3(16, 4, 16), 256, 0, stream>>>(x, coef, qpart);
    kernelBfin<<<dim3(16, 16), 256, 0, stream>>>(qpart, bases, ctc, btb[(t + 1) & 1]);
  }

  // final compute_coef with bases_7 / BtB[1], then reconstruct
  kernelA<<<dim3(32, 16, 2), 256, 0, stream>>>(x, bases, Ppart, ctc);
  kernelCU<<<32, 256, 0, stream>>>(coef, Ppart, btb[1], btb[0], ctc);
  kernelOut<<<dim3(4, 16, 16), 256, 0, stream>>>(bases, coef, out);
}

// Round 4
// 977.397 us; speedup vs baseline: 1.6349x; 1.6349x over previous
//
#include <hip/hip_runtime.h>

#define EPS 1e-6f

// DPP helper: v += v rotated by CTRL within each 16-lane row (row_ror:n = 0x120+n)
template <int CTRL>
__device__ __forceinline__ float dpp_add(float v) {
  int moved = __builtin_amdgcn_update_dpp(0, __float_as_int(v), CTRL, 0xF, 0xF, false);
  return v + __int_as_float(moved);
}

// ---------------------------------------------------------------------------
// Kernel A: Ppart[h][b][n][r] = sum_{d in half h} x[b,n,d] * bases[b,d,r]
// grid (64 grp, 16 b, 2 h) = 2048 blocks; block 256 = 4 waves; wave owns 2 n.
// T3/T4 pipeline (m201 idiom): 16 chunks of 128 d; bases staged via
// global_load_lds into a TRIPLE-buffered 3x8KB LDS ring (triple buffer kills
// the WAR race of stage(c+2) vs readers of buf[c]); x prefetched 2 chunks
// ahead in regs; raw s_barrier with counted vmcnt(6) -- stage(c+1) and two x
// generations stay in flight ACROSS the barrier (no vmcnt(0) drain convoy,
// which r0-r2 showed is the 81us ceiling).
// Swizzle (rule #21, both-sides): LDS dest linear; global SOURCE quad
// pre-swizzled q_phys = q ^ ((row>>1)&3); ds_read applies the same XOR
// (row>>1 == lane for rows 2*lane,2*lane+1) -> <=few-way bank conflict.
// acc[2][16] = 32 VGPR; launch_bounds (256,5) leaves VGPR headroom (r2
// lesson: a forced-fit allocator spills -> 127MB of scratch writes).
// ---------------------------------------------------------------------------
__global__ __launch_bounds__(256, 5) void kernelA(
    const float* __restrict__ x, const float* __restrict__ bases,
    float* __restrict__ Ppart, float* __restrict__ CtC)
{
  __shared__ __align__(16) float lb[3 * 2048];  // 3 x 8 KB ring
  const int tid = threadIdx.x;
  const int grp = blockIdx.x;
  const int b = blockIdx.y;
  const int h = blockIdx.z;
  if (h == 0 && grp == 0) CtC[b * 256 + tid] = 0.0f;
  const int w = tid >> 6;
  const int lane = tid & 63;
  const int n0 = grp * 8 + w * 2;
  const float* __restrict__ xp =
      x + ((size_t)(b * 512 + n0)) * 4096 + h * 2048 + lane * 2;

  // stage addressing: slot idx = tid -> row = tid>>2, qphys = tid&3;
  // stored logical quad qlog = (tid&3) ^ ((row>>1)&3) = (tid&3) ^ ((tid>>3)&3)
  const int rowt = tid >> 2;
  const int qlog = (tid & 3) ^ ((tid >> 3) & 3);
  const float* __restrict__ gb = bases + ((size_t)(b * 4096 + h * 2048)) * 16;
  float* __restrict__ ldst = lb + (tid & 192) * 4;  // wave-uniform dest base

#define STAGE_A(buf, c) do {                                                   \
    const float* g0 = gb + (size_t)((c) * 128 + rowt) * 16 + qlog * 4;         \
    __builtin_amdgcn_global_load_lds(                                          \
        (const __attribute__((address_space(1))) unsigned*)(g0),               \
        (__attribute__((address_space(3))) unsigned*)(ldst + (buf) * 2048),    \
        16, 0, 0);                                                             \
    __builtin_amdgcn_global_load_lds(                                          \
        (const __attribute__((address_space(1))) unsigned*)(g0 + 1024),        \
        (__attribute__((address_space(3))) unsigned*)(ldst + (buf) * 2048 + 1024), \
        16, 0, 0);                                                             \
  } while (0)

  float acc[2][16];
#pragma unroll
  for (int i = 0; i < 2; ++i)
#pragma unroll
    for (int r = 0; r < 16; ++r) acc[i][r] = 0.0f;

  float2 xA[2], xB[2], xC[2];

  // prologue: S(0), then X(0), X(1)  (issue order pinned: S before X)
  STAGE_A(0, 0);
  __builtin_amdgcn_sched_barrier(0);
  xA[0] = *(const float2*)(xp);
  xA[1] = *(const float2*)(xp + 4096);
  xB[0] = *(const float2*)(xp + 128);
  xB[1] = *(const float2*)(xp + 4096 + 128);
  __builtin_amdgcn_sched_barrier(0);

  int bcur = 0;
  for (int c = 0; c < 16; ++c) {
    const int bnext = (bcur == 2) ? 0 : bcur + 1;
    if (c + 1 < 16) STAGE_A(bnext, c + 1);          // S(c+1)
    __builtin_amdgcn_sched_barrier(0);
    if (c + 2 < 16) {                                // X(c+2)
      xC[0] = *(const float2*)(xp + (c + 2) * 128);
      xC[1] = *(const float2*)(xp + 4096 + (c + 2) * 128);
    }
    __builtin_amdgcn_sched_barrier(0);
    // steady state outstanding here: X(c),S(c),X(c+1),S(c+1),X(c+2) = 10 ops;
    // vmcnt(6) completes X(c),S(c) and keeps the 6 newest in flight.
    if (c < 14)       asm volatile("s_waitcnt vmcnt(6)" ::: "memory");
    else if (c == 14) asm volatile("s_waitcnt vmcnt(4)" ::: "memory");
    else              asm volatile("s_waitcnt vmcnt(0)" ::: "memory");
    __builtin_amdgcn_s_barrier();
    __builtin_amdgcn_sched_barrier(0);

    const float* __restrict__ bufc = lb + bcur * 2048;
    const int sw = lane & 3;
#pragma unroll
    for (int k = 0; k < 2; ++k) {
      const float* __restrict__ br = bufc + (lane * 2 + k) * 16;
      float4 q0 = *(const float4*)(br + ((0 ^ sw) << 2));
      float4 q1 = *(const float4*)(br + ((1 ^ sw) << 2));
      float4 q2 = *(const float4*)(br + ((2 ^ sw) << 2));
      float4 q3 = *(const float4*)(br + ((3 ^ sw) << 2));
      const float x0 = k ? xA[0].y : xA[0].x;
      const float x1 = k ? xA[1].y : xA[1].x;
      acc[0][0]  = fmaf(x0, q0.x, acc[0][0]);
      acc[0][1]  = fmaf(x0, q0.y, acc[0][1]);
      acc[0][2]  = fmaf(x0, q0.z, acc[0][2]);
      acc[0][3]  = fmaf(x0, q0.w, acc[0][3]);
      acc[0][4]  = fmaf(x0, q1.x, acc[0][4]);
      acc[0][5]  = fmaf(x0, q1.y, acc[0][5]);
      acc[0][6]  = fmaf(x0, q1.z, acc[0][6]);
      acc[0][7]  = fmaf(x0, q1.w, acc[0][7]);
      acc[0][8]  = fmaf(x0, q2.x, acc[0][8]);
      acc[0][9]  = fmaf(x0, q2.y, acc[0][9]);
      acc[0][10] = fmaf(x0, q2.z, acc[0][10]);
      acc[0][11] = fmaf(x0, q2.w, acc[0][11]);
      acc[0][12] = fmaf(x0, q3.x, acc[0][12]);
      acc[0][13] = fmaf(x0, q3.y, acc[0][13]);
      acc[0][14] = fmaf(x0, q3.z, acc[0][14]);
      acc[0][15] = fmaf(x0, q3.w, acc[0][15]);
      acc[1][0]  = fmaf(x1, q0.x, acc[1][0]);
      acc[1][1]  = fmaf(x1, q0.y, acc[1][1]);
      acc[1][2]  = fmaf(x1, q0.z, acc[1][2]);
      acc[1][3]  = fmaf(x1, q0.w, acc[1][3]);
      acc[1][4]  = fmaf(x1, q1.x, acc[1][4]);
      acc[1][5]  = fmaf(x1, q1.y, acc[1][5]);
      acc[1][6]  = fmaf(x1, q1.z, acc[1][6]);
      acc[1][7]  = fmaf(x1, q1.w, acc[1][7]);
      acc[1][8]  = fmaf(x1, q2.x, acc[1][8]);
      acc[1][9]  = fmaf(x1, q2.y, acc[1][9]);
      acc[1][10] = fmaf(x1, q2.z, acc[1][10]);
      acc[1][11] = fmaf(x1, q2.w, acc[1][11]);
      acc[1][12] = fmaf(x1, q3.x, acc[1][12]);
      acc[1][13] = fmaf(x1, q3.y, acc[1][13]);
      acc[1][14] = fmaf(x1, q3.z, acc[1][14]);
      acc[1][15] = fmaf(x1, q3.w, acc[1][15]);
    }
#pragma unroll
    for (int i = 0; i < 2; ++i) { xA[i] = xB[i]; xB[i] = xC[i]; }
    bcur = bnext;
  }
#undef STAGE_A

  // butterfly-reduce each acc over the 64 lanes (all lanes end with the sum)
#pragma unroll
  for (int i = 0; i < 2; ++i)
#pragma unroll
    for (int r = 0; r < 16; ++r) {
      float v = acc[i][r];
      v = dpp_add<0x121>(v);
      v = dpp_add<0x122>(v);
      v = dpp_add<0x124>(v);
      v = dpp_add<0x128>(v);
      v += __shfl_xor(v, 16, 64);
      v += __shfl_xor(v, 32, 64);
      acc[i][r] = v;
    }

  if (lane == 0) {
    float* __restrict__ pp =
        Ppart + (((size_t)(h * 16 + b)) * 512 + n0) * 16;
#pragma unroll
    for (int i = 0; i < 2; ++i) {
#pragma unroll
      for (int q = 0; q < 4; ++q)
        *(float4*)(pp + i * 16 + q * 4) =
            make_float4(acc[i][q * 4], acc[i][q * 4 + 1], acc[i][q * 4 + 2], acc[i][q * 4 + 3]);
    }
  }
}

// ---------------------------------------------------------------------------
// Softmax init: coef[b,n,:] = softmax(100 * (Ppart0 + Ppart1)[b,n,:])
// grid 32 x 256; thread = one n row.
// ---------------------------------------------------------------------------
__global__ __launch_bounds__(256) void kernelSM(
    const float* __restrict__ Ppart, float* __restrict__ coef)
{
  const int gid = blockIdx.x * 256 + threadIdx.x;  // 0..8191
  const int b = gid >> 9, n = gid & 511;
  const float* __restrict__ p0 = Ppart + (((size_t)b) * 512 + n) * 16;
  const float* __restrict__ p1 = Ppart + (((size_t)(16 + b)) * 512 + n) * 16;
  float p[16];
#pragma unroll
  for (int r = 0; r < 16; ++r) p[r] = p0[r] + p1[r];
  float m = p[0];
#pragma unroll
  for (int r = 1; r < 16; ++r) m = fmaxf(m, p[r]);
  float e[16];
  float s = 0.0f;
#pragma unroll
  for (int r = 0; r < 16; ++r) { e[r] = __expf(100.0f * (p[r] - m)); s += e[r]; }
  float inv = 1.0f / s;
  float* __restrict__ crow = coef + (((size_t)b) * 512 + n) * 16;
#pragma unroll
  for (int r = 0; r < 16; ++r) crow[r] = e[r] * inv;
}

// ---------------------------------------------------------------------------
// Standalone gram (used once for BtB0): out[b,s*16+r] += sum_l M[.,r]*M[.,s]
// ---------------------------------------------------------------------------
__global__ __launch_bounds__(256) void kernelGram(
    const float* __restrict__ M, float* __restrict__ out, int L)
{
  __shared__ __align__(16) float sm[256 * 20];
  __shared__ __align__(16) float part[4 * 272];
  const int tid = threadIdx.x;
  const int b = blockIdx.y;
  const int sl = blockIdx.x;
  const float4* __restrict__ src = (const float4*)(M + ((size_t)b * L + (size_t)sl * 256) * 16);
#pragma unroll
  for (int k = 0; k < 4; ++k) {
    int idx = k * 256 + tid;
    int row = idx >> 2, q = idx & 3;
    *(float4*)(&sm[row * 20 + q * 4]) = src[idx];
  }
  __syncthreads();
  const int rq = tid & 3;
  const int s = (tid >> 2) & 15;
  const int g = tid >> 6;
  float a0 = 0.f, a1 = 0.f, a2 = 0.f, a3 = 0.f;
#pragma unroll 4
  for (int l = g * 64; l < g * 64 + 64; ++l) {
    float4 bv = *(const float4*)(&sm[l * 20 + rq * 4]);
    float cs = sm[l * 20 + s];
    a0 = fmaf(cs, bv.x, a0);
    a1 = fmaf(cs, bv.y, a1);
    a2 = fmaf(cs, bv.z, a2);
    a3 = fmaf(cs, bv.w, a3);
  }
  *(float4*)(&part[g * 272 + s * 16 + rq * 4]) = make_float4(a0, a1, a2, a3);
  __syncthreads();
  float v = part[0 * 272 + tid] + part[1 * 272 + tid] + part[2 * 272 + tid] + part[3 * 272 + tid];
  atomicAdd(out + b * 256 + tid, v);
}

// ---------------------------------------------------------------------------
// Coef update + fused CtC gram: coef *= (P0+P1) / (coef BtB + eps); CtC += gram
// grid 32; block 256 (thread = one n row). Also zeros BtBz.
// ---------------------------------------------------------------------------
__global__ __launch_bounds__(256) void kernelCU(
    float* __restrict__ coef, const float* __restrict__ Ppart,
    const float* __restrict__ BtBr, float* __restrict__ BtBz,
    float* __restrict__ CtCadd)
{
  __shared__ __align__(16) float sm[256 * 20 + 4 * 272];
  const int tid = threadIdx.x;
  BtBz[blockIdx.x * 128 + (tid & 127)] = 0.0f;
  const int b = blockIdx.x >> 1;
  const int n = ((blockIdx.x & 1) << 8) + tid;
  float* __restrict__ crow = coef + ((size_t)(b * 512 + n)) * 16;
  const float* __restrict__ p0 = Ppart + (((size_t)b) * 512 + n) * 16;
  const float* __restrict__ p1 = Ppart + (((size_t)(16 + b)) * 512 + n) * 16;
  const float* __restrict__ btb = BtBr + b * 256;
  float cv[16], den[16];
#pragma unroll
  for (int r = 0; r < 16; ++r) cv[r] = crow[r];
#pragma unroll
  for (int r = 0; r < 16; ++r) den[r] = 0.f;
#pragma unroll
  for (int s2 = 0; s2 < 16; ++s2) {
    const float bs = cv[s2];
#pragma unroll
    for (int r = 0; r < 16; ++r) den[r] = fmaf(bs, btb[s2 * 16 + r], den[r]);
  }
#pragma unroll
  for (int r = 0; r < 16; ++r) {
    float cn = cv[r] * (p0[r] + p1[r]) / (den[r] + EPS);
    crow[r] = cn;
    sm[tid * 20 + r] = cn;
  }
  __syncthreads();
  const int rq = tid & 3;
  const int s = (tid >> 2) & 15;
  const int g = tid >> 6;
  float a0 = 0.f, a1 = 0.f, a2 = 0.f, a3 = 0.f;
#pragma unroll 4
  for (int l = g * 64; l < g * 64 + 64; ++l) {
    float4 bv = *(const float4*)(&sm[l * 20 + rq * 4]);
    float cs = sm[l * 20 + s];
    a0 = fmaf(cs, bv.x, a0);
    a1 = fmaf(cs, bv.y, a1);
    a2 = fmaf(cs, bv.z, a2);
    a3 = fmaf(cs, bv.w, a3);
  }
  float* part = sm + 5120;
  *(float4*)(&part[g * 272 + s * 16 + rq * 4]) = make_float4(a0, a1, a2, a3);
  __syncthreads();
  float v = part[0 * 272 + tid] + part[1 * 272 + tid] + part[2 * 272 + tid] + part[3 * 272 + tid];
  atomicAdd(CtCadd + b * 256 + tid, v);
}

// ---------------------------------------------------------------------------
// Kernel B accumulate: qpart[ns][b][d][r] = sum_{n in slice} x[b,n,d]*coef[b,n,r]
// grid (16 d-tiles, 4 n-slices, 16 b) = 1024 blocks (round-0 form).
// ---------------------------------------------------------------------------
__global__ __launch_bounds__(256) void kernelBacc(
    const float* __restrict__ x, const float* __restrict__ coef,
    float* __restrict__ qpart)
{
  const int tid = threadIdx.x;
  const int dt = blockIdx.x, ns = blockIdx.y, b = blockIdx.z;
  const int d = dt * 256 + tid;
  const float* __restrict__ xp = x + ((size_t)(b * 512 + ns * 128)) * 4096 + d;
  const float* __restrict__ cp = coef + ((size_t)(b * 512 + ns * 128)) * 16;
  float acc[16];
#pragma unroll
  for (int r = 0; r < 16; ++r) acc[r] = 0.f;
#pragma unroll 4
  for (int n = 0; n < 128; ++n) {
    const float xv = xp[(size_t)n * 4096];
    const float* __restrict__ crow = cp + n * 16;   // wave-uniform -> s_load
#pragma unroll
    for (int r = 0; r < 16; ++r) acc[r] = fmaf(xv, crow[r], acc[r]);
  }
  float* __restrict__ qp = qpart + (((size_t)(ns * 16 + b)) * 4096 + d) * 16;
#pragma unroll
  for (int q = 0; q < 4; ++q)
    *(float4*)(qp + q * 4) = make_float4(acc[q * 4], acc[q * 4 + 1], acc[q * 4 + 2], acc[q * 4 + 3]);
}

// ---------------------------------------------------------------------------
// Kernel B finalize + fused BtB gram.
// grid (16 d-tiles, 16 b); block 256 (thread = one d).
// ---------------------------------------------------------------------------
__global__ __launch_bounds__(256) void kernelBfin(
    const float* __restrict__ qpart, float* __restrict__ bases,
    const float* __restrict__ CtC, float* __restrict__ BtBadd)
{
  __shared__ __align__(16) float sm[256 * 20 + 4 * 272];
  const int tid = threadIdx.x;
  const int dt = blockIdx.x, b = blockIdx.y;
  const int d = dt * 256 + tid;
  float acc[16];
#pragma unroll
  for (int r = 0; r < 16; ++r) acc[r] = 0.f;
#pragma unroll
  for (int ns = 0; ns < 4; ++ns) {
    const float* __restrict__ qp = qpart + (((size_t)(ns * 16 + b)) * 4096 + d) * 16;
#pragma unroll
    for (int q = 0; q < 4; ++q) {
      float4 v = *(const float4*)(qp + q * 4);
      acc[q * 4 + 0] += v.x; acc[q * 4 + 1] += v.y; acc[q * 4 + 2] += v.z; acc[q * 4 + 3] += v.w;
    }
  }
  float* __restrict__ brow = bases + ((size_t)(b * 4096 + d)) * 16;
  float bv[16];
#pragma unroll
  for (int r = 0; r < 16; ++r) bv[r] = brow[r];
  const float* __restrict__ ctc = CtC + b * 256;
  float den[16];
#pragma unroll
  for (int r = 0; r < 16; ++r) den[r] = 0.f;
#pragma unroll
  for (int s2 = 0; s2 < 16; ++s2) {
    const float bs = bv[s2];
#pragma unroll
    for (int r = 0; r < 16; ++r) den[r] = fmaf(bs, ctc[s2 * 16 + r], den[r]);
  }
#pragma unroll
  for (int r = 0; r < 16; ++r) {
    float bn = bv[r] * acc[r] / (den[r] + EPS);
    brow[r] = bn;
    sm[tid * 20 + r] = bn;
  }
  __syncthreads();
  const int rq = tid & 3;
  const int s = (tid >> 2) & 15;
  const int g = tid >> 6;
  float a0 = 0.f, a1 = 0.f, a2 = 0.f, a3 = 0.f;
#pragma unroll 4
  for (int l = g * 64; l < g * 64 + 64; ++l) {
    float4 bq = *(const float4*)(&sm[l * 20 + rq * 4]);
    float cs = sm[l * 20 + s];
    a0 = fmaf(cs, bq.x, a0);
    a1 = fmaf(cs, bq.y, a1);
    a2 = fmaf(cs, bq.z, a2);
    a3 = fmaf(cs, bq.w, a3);
  }
  float* part = sm + 5120;
  *(float4*)(&part[g * 272 + s * 16 + rq * 4]) = make_float4(a0, a1, a2, a3);
  __syncthreads();
  float v = part[0 * 272 + tid] + part[1 * 272 + tid] + part[2 * 272 + tid] + part[3 * 272 + tid];
  atomicAdd(BtBadd + b * 256 + tid, v);
}

// ---------------------------------------------------------------------------
// Output: out[b,n,d] = sum_r bases[b,d,r]*coef[b,n,r]
// grid (4 d-tiles, 16 n-slices, 16 b); thread owns 4 d (float4 stores).
// ---------------------------------------------------------------------------
__global__ __launch_bounds__(256) void kernelOut(
    const float* __restrict__ bases, const float* __restrict__ coef,
    float* __restrict__ out)
{
  const int tid = threadIdx.x;
  const int dt = blockIdx.x, ns = blockIdx.y, b = blockIdx.z;
  const int d0 = dt * 1024 + tid * 4;
  float bv[4][16];
#pragma unroll
  for (int k = 0; k < 4; ++k) {
    const float* __restrict__ brow = bases + ((size_t)(b * 4096 + d0 + k)) * 16;
#pragma unroll
    for (int r = 0; r < 16; ++r) bv[k][r] = brow[r];
  }
  const float* __restrict__ cp = coef + ((size_t)(b * 512 + ns * 32)) * 16;
  float* __restrict__ op = out + ((size_t)(b * 512 + ns * 32)) * 4096 + d0;
#pragma unroll 4
  for (int n = 0; n < 32; ++n) {
    const float* __restrict__ crow = cp + n * 16;
    float v[4];
#pragma unroll
    for (int k = 0; k < 4; ++k) {
      float s = 0.f;
#pragma unroll
      for (int r = 0; r < 16; ++r) s = fmaf(bv[k][r], crow[r], s);
      v[k] = s;
    }
    *(float4*)(op + (size_t)n * 4096) = make_float4(v[0], v[1], v[2], v[3]);
  }
}

// ---------------------------------------------------------------------------
extern "C" void kernel_launch(void* const* d_in, const int* in_sizes, int n_in,
                              void* d_out, int out_size, void* d_ws, size_t ws_size,
                              hipStream_t stream) {
  const float* x = (const float*)d_in[0];         // 16*512*4096
  const float* bases_in = (const float*)d_in[1];  // 16*4096*16
  float* out = (float*)d_out;
  float* ws = (float*)d_ws;

  float* bases = ws;               // 1,048,576 floats
  float* coef  = bases + 1048576;  // 131,072
  float* Ppart = coef + 131072;    // 262,144 (2 d-half partials)
  float* btb0  = Ppart + 262144;   // 4,096
  float* btb1  = btb0 + 4096;      // 4,096
  float* ctc   = btb1 + 4096;      // 4,096
  float* qpart = ctc + 4096;       // 4*16*4096*16 = 4,194,304
  float* btb[2] = {btb0, btb1};

  hipMemsetAsync(btb0, 0, 4096 * sizeof(float), stream);
  hipMemcpyAsync(bases, bases_in, 1048576 * sizeof(float),
                 hipMemcpyDeviceToDevice, stream);

  // init: Ppart = X^T B0 (+ctc zero), coef = softmax(100*P); BtB0 = gram(B0)
  kernelA<<<dim3(64, 16, 2), 256, 0, stream>>>(x, bases, Ppart, ctc);
  kernelSM<<<32, 256, 0, stream>>>(Ppart, coef);
  kernelGram<<<dim3(16, 16), 256, 0, stream>>>(bases, btb0, 4096);

  for (int t = 0; t < 7; ++t) {
    if (t > 0) kernelA<<<dim3(64, 16, 2), 256, 0, stream>>>(x, bases, Ppart, ctc);
    kernelCU<<<32, 256, 0, stream>>>(coef, Ppart, btb[t & 1], btb[(t + 1) & 1], ctc);
    kernelBacc<<<dim3(16, 4, 16), 256, 0, stream>>>(x, coef, qpart);
    kernelBfin<<<dim3(16, 16), 256, 0, stream>>>(qpart, bases, ctc, btb[(t + 1) & 1]);
  }

  // final compute_coef with bases_7 / BtB[1], then reconstruct
  kernelA<<<dim3(64, 16, 2), 256, 0, stream>>>(x, bases, Ppart, ctc);
  kernelCU<<<32, 256, 0, stream>>>(coef, Ppart, btb[1], btb[0], ctc);
  kernelOut<<<dim3(4, 16, 16), 256, 0, stream>>>(bases, coef, out);
}

// Round 5
// 971.291 us; speedup vs baseline: 1.6452x; 1.0063x over previous
//
#include <hip/hip_runtime.h>

#define EPS 1e-6f

// DPP helper: v += v rotated by CTRL within each 16-lane row (row_ror:n = 0x120+n)
template <int CTRL>
__device__ __forceinline__ float dpp_add(float v) {
  int moved = __builtin_amdgcn_update_dpp(0, __float_as_int(v), CTRL, 0xF, 0xF, false);
  return v + __int_as_float(moved);
}

// ---------------------------------------------------------------------------
// Transpose: bT[b][r][d] = bases_in[b][d][r].  Runs once.
// grid (16 d-slices, 16 b); block 256. Thread loads one full d-row (16 floats,
// coalesced dwordx4), LDS-transposes, writes 16 consecutive d per thread.
// ---------------------------------------------------------------------------
__global__ __launch_bounds__(256) void kernelT(
    const float* __restrict__ bin, float* __restrict__ bT)
{
  __shared__ float t[256][17];
  const int tid = threadIdx.x;
  const int ds = blockIdx.x;
  const int b = blockIdx.y;
  const float4* __restrict__ src =
      (const float4*)(bin + ((size_t)(b * 4096 + ds * 256 + tid)) * 16);
  float4 a0 = src[0], a1 = src[1], a2 = src[2], a3 = src[3];
  t[tid][0] = a0.x;  t[tid][1] = a0.y;  t[tid][2] = a0.z;  t[tid][3] = a0.w;
  t[tid][4] = a1.x;  t[tid][5] = a1.y;  t[tid][6] = a1.z;  t[tid][7] = a1.w;
  t[tid][8] = a2.x;  t[tid][9] = a2.y;  t[tid][10] = a2.z; t[tid][11] = a2.w;
  t[tid][12] = a3.x; t[tid][13] = a3.y; t[tid][14] = a3.z; t[tid][15] = a3.w;
  __syncthreads();
  const int r = tid >> 4;
  const int i0 = (tid & 15) * 16;
  float* __restrict__ dst = bT + ((size_t)(b * 16 + r)) * 4096 + ds * 256 + i0;
#pragma unroll
  for (int j = 0; j < 16; ++j) dst[j] = t[i0 + j][r];
}

// ---------------------------------------------------------------------------
// Kernel A: Ppart[h][b][n][r] = sum_{d in half h} x[b,n,d] * bases[b,d,r]
// grid (32 grp, 16 b, 2 h) = 1024 blocks; block 256 = 4 waves; wave owns 4 n.
// v3: NO LDS, NO barriers. Reads the r-major transposed bT so BOTH x and
// bases loads are coalesced dwordx4 along d (lane owns 4 contiguous d).
// r0/r1/r4 post-mortem: every barrier-staged variant pinned at 77-81 us
// (stage lead < HBM latency; barrier convoy). Pure streaming lets waves slip
// and the compiler software-pipeline. x prefetched one chunk ahead.
// acc[4][16]=64 + xv/xn 32 + bq 16 ~ 130 VGPR; launch_bounds(256,3) caps 170.
// Blocks (grp==0, h==0) also zero CtC for the fused coef-gram.
// ---------------------------------------------------------------------------
__global__ __launch_bounds__(256, 3) void kernelA(
    const float* __restrict__ x, const float* __restrict__ bT,
    float* __restrict__ Ppart, float* __restrict__ CtC)
{
  const int tid = threadIdx.x;
  const int grp = blockIdx.x;
  const int b = blockIdx.y;
  const int h = blockIdx.z;
  if (h == 0 && grp == 0) CtC[b * 256 + tid] = 0.0f;
  const int w = tid >> 6;
  const int lane = tid & 63;
  const int n0 = grp * 16 + w * 4;
  const float* __restrict__ xp =
      x + ((size_t)(b * 512 + n0)) * 4096 + h * 2048 + lane * 4;
  const float* __restrict__ bp =
      bT + ((size_t)(b * 16)) * 4096 + h * 2048 + lane * 4;

  float acc[4][16];
#pragma unroll
  for (int i = 0; i < 4; ++i)
#pragma unroll
    for (int r = 0; r < 16; ++r) acc[i][r] = 0.0f;

  float4 xv[4], xn[4];
#pragma unroll
  for (int i = 0; i < 4; ++i) xv[i] = *(const float4*)(xp + (size_t)i * 4096);

  for (int c = 0; c < 8; ++c) {
    if (c < 7) {
#pragma unroll
      for (int i = 0; i < 4; ++i)
        xn[i] = *(const float4*)(xp + (size_t)i * 4096 + (c + 1) * 256);
    }
#pragma unroll
    for (int rg = 0; rg < 4; ++rg) {
      float4 bq[4];
#pragma unroll
      for (int j = 0; j < 4; ++j)
        bq[j] = *(const float4*)(bp + (size_t)(rg * 4 + j) * 4096 + c * 256);
#pragma unroll
      for (int i = 0; i < 4; ++i) {
#pragma unroll
        for (int j = 0; j < 4; ++j) {
          float s = acc[i][rg * 4 + j];
          s = fmaf(xv[i].x, bq[j].x, s);
          s = fmaf(xv[i].y, bq[j].y, s);
          s = fmaf(xv[i].z, bq[j].z, s);
          s = fmaf(xv[i].w, bq[j].w, s);
          acc[i][rg * 4 + j] = s;
        }
      }
    }
#pragma unroll
    for (int i = 0; i < 4; ++i) xv[i] = xn[i];
  }

  // butterfly-reduce each acc over the 64 lanes (all lanes end with the sum)
#pragma unroll
  for (int i = 0; i < 4; ++i)
#pragma unroll
    for (int r = 0; r < 16; ++r) {
      float v = acc[i][r];
      v = dpp_add<0x121>(v);
      v = dpp_add<0x122>(v);
      v = dpp_add<0x124>(v);
      v = dpp_add<0x128>(v);
      v += __shfl_xor(v, 16, 64);
      v += __shfl_xor(v, 32, 64);
      acc[i][r] = v;
    }

  if (lane == 0) {
    float* __restrict__ pp =
        Ppart + (((size_t)(h * 16 + b)) * 512 + n0) * 16;
#pragma unroll
    for (int i = 0; i < 4; ++i) {
#pragma unroll
      for (int q = 0; q < 4; ++q)
        *(float4*)(pp + i * 16 + q * 4) =
            make_float4(acc[i][q * 4], acc[i][q * 4 + 1], acc[i][q * 4 + 2], acc[i][q * 4 + 3]);
    }
  }
}

// ---------------------------------------------------------------------------
// Softmax init: coef[b,n,:] = softmax(100 * (Ppart0 + Ppart1)[b,n,:])
// grid 32 x 256; thread = one n row.
// ---------------------------------------------------------------------------
__global__ __launch_bounds__(256) void kernelSM(
    const float* __restrict__ Ppart, float* __restrict__ coef)
{
  const int gid = blockIdx.x * 256 + threadIdx.x;  // 0..8191
  const int b = gid >> 9, n = gid & 511;
  const float* __restrict__ p0 = Ppart + (((size_t)b) * 512 + n) * 16;
  const float* __restrict__ p1 = Ppart + (((size_t)(16 + b)) * 512 + n) * 16;
  float p[16];
#pragma unroll
  for (int r = 0; r < 16; ++r) p[r] = p0[r] + p1[r];
  float m = p[0];
#pragma unroll
  for (int r = 1; r < 16; ++r) m = fmaxf(m, p[r]);
  float e[16];
  float s = 0.0f;
#pragma unroll
  for (int r = 0; r < 16; ++r) { e[r] = __expf(100.0f * (p[r] - m)); s += e[r]; }
  float inv = 1.0f / s;
  float* __restrict__ crow = coef + (((size_t)b) * 512 + n) * 16;
#pragma unroll
  for (int r = 0; r < 16; ++r) crow[r] = e[r] * inv;
}

// ---------------------------------------------------------------------------
// Standalone gram (used once for BtB0): out[b,s*16+r] += sum_l M[.,r]*M[.,s]
// ---------------------------------------------------------------------------
__global__ __launch_bounds__(256) void kernelGram(
    const float* __restrict__ M, float* __restrict__ out, int L)
{
  __shared__ __align__(16) float sm[256 * 20];
  __shared__ __align__(16) float part[4 * 272];
  const int tid = threadIdx.x;
  const int b = blockIdx.y;
  const int sl = blockIdx.x;
  const float4* __restrict__ src = (const float4*)(M + ((size_t)b * L + (size_t)sl * 256) * 16);
#pragma unroll
  for (int k = 0; k < 4; ++k) {
    int idx = k * 256 + tid;
    int row = idx >> 2, q = idx & 3;
    *(float4*)(&sm[row * 20 + q * 4]) = src[idx];
  }
  __syncthreads();
  const int rq = tid & 3;
  const int s = (tid >> 2) & 15;
  const int g = tid >> 6;
  float a0 = 0.f, a1 = 0.f, a2 = 0.f, a3 = 0.f;
#pragma unroll 4
  for (int l = g * 64; l < g * 64 + 64; ++l) {
    float4 bv = *(const float4*)(&sm[l * 20 + rq * 4]);
    float cs = sm[l * 20 + s];
    a0 = fmaf(cs, bv.x, a0);
    a1 = fmaf(cs, bv.y, a1);
    a2 = fmaf(cs, bv.z, a2);
    a3 = fmaf(cs, bv.w, a3);
  }
  *(float4*)(&part[g * 272 + s * 16 + rq * 4]) = make_float4(a0, a1, a2, a3);
  __syncthreads();
  float v = part[0 * 272 + tid] + part[1 * 272 + tid] + part[2 * 272 + tid] + part[3 * 272 + tid];
  atomicAdd(out + b * 256 + tid, v);
}

// ---------------------------------------------------------------------------
// Coef update + fused CtC gram: coef *= (P0+P1) / (coef BtB + eps); CtC += gram
// grid 32; block 256 (thread = one n row). Also zeros BtBz.
// ---------------------------------------------------------------------------
__global__ __launch_bounds__(256) void kernelCU(
    float* __restrict__ coef, const float* __restrict__ Ppart,
    const float* __restrict__ BtBr, float* __restrict__ BtBz,
    float* __restrict__ CtCadd)
{
  __shared__ __align__(16) float sm[256 * 20 + 4 * 272];
  const int tid = threadIdx.x;
  BtBz[blockIdx.x * 128 + (tid & 127)] = 0.0f;
  const int b = blockIdx.x >> 1;
  const int n = ((blockIdx.x & 1) << 8) + tid;
  float* __restrict__ crow = coef + ((size_t)(b * 512 + n)) * 16;
  const float* __restrict__ p0 = Ppart + (((size_t)b) * 512 + n) * 16;
  const float* __restrict__ p1 = Ppart + (((size_t)(16 + b)) * 512 + n) * 16;
  const float* __restrict__ btb = BtBr + b * 256;
  float cv[16], den[16];
#pragma unroll
  for (int r = 0; r < 16; ++r) cv[r] = crow[r];
#pragma unroll
  for (int r = 0; r < 16; ++r) den[r] = 0.f;
#pragma unroll
  for (int s2 = 0; s2 < 16; ++s2) {
    const float bs = cv[s2];
#pragma unroll
    for (int r = 0; r < 16; ++r) den[r] = fmaf(bs, btb[s2 * 16 + r], den[r]);
  }
#pragma unroll
  for (int r = 0; r < 16; ++r) {
    float cn = cv[r] * (p0[r] + p1[r]) / (den[r] + EPS);
    crow[r] = cn;
    sm[tid * 20 + r] = cn;
  }
  __syncthreads();
  const int rq = tid & 3;
  const int s = (tid >> 2) & 15;
  const int g = tid >> 6;
  float a0 = 0.f, a1 = 0.f, a2 = 0.f, a3 = 0.f;
#pragma unroll 4
  for (int l = g * 64; l < g * 64 + 64; ++l) {
    float4 bv = *(const float4*)(&sm[l * 20 + rq * 4]);
    float cs = sm[l * 20 + s];
    a0 = fmaf(cs, bv.x, a0);
    a1 = fmaf(cs, bv.y, a1);
    a2 = fmaf(cs, bv.z, a2);
    a3 = fmaf(cs, bv.w, a3);
  }
  float* part = sm + 5120;
  *(float4*)(&part[g * 272 + s * 16 + rq * 4]) = make_float4(a0, a1, a2, a3);
  __syncthreads();
  float v = part[0 * 272 + tid] + part[1 * 272 + tid] + part[2 * 272 + tid] + part[3 * 272 + tid];
  atomicAdd(CtCadd + b * 256 + tid, v);
}

// ---------------------------------------------------------------------------
// Kernel B accumulate: qpart[ns][b][d][r] = sum_{n in slice} x[b,n,d]*coef[b,n,r]
// grid (16 d-tiles, 4 n-slices, 16 b) = 1024 blocks (round-0 form).
// ---------------------------------------------------------------------------
__global__ __launch_bounds__(256) void kernelBacc(
    const float* __restrict__ x, const float* __restrict__ coef,
    float* __restrict__ qpart)
{
  const int tid = threadIdx.x;
  const int dt = blockIdx.x, ns = blockIdx.y, b = blockIdx.z;
  const int d = dt * 256 + tid;
  const float* __restrict__ xp = x + ((size_t)(b * 512 + ns * 128)) * 4096 + d;
  const float* __restrict__ cp = coef + ((size_t)(b * 512 + ns * 128)) * 16;
  float acc[16];
#pragma unroll
  for (int r = 0; r < 16; ++r) acc[r] = 0.f;
#pragma unroll 4
  for (int n = 0; n < 128; ++n) {
    const float xv = xp[(size_t)n * 4096];
    const float* __restrict__ crow = cp + n * 16;   // wave-uniform -> s_load
#pragma unroll
    for (int r = 0; r < 16; ++r) acc[r] = fmaf(xv, crow[r], acc[r]);
  }
  float* __restrict__ qp = qpart + (((size_t)(ns * 16 + b)) * 4096 + d) * 16;
#pragma unroll
  for (int q = 0; q < 4; ++q)
    *(float4*)(qp + q * 4) = make_float4(acc[q * 4], acc[q * 4 + 1], acc[q * 4 + 2], acc[q * 4 + 3]);
}

// ---------------------------------------------------------------------------
// Kernel B finalize + fused BtB gram. Writes BOTH bases layouts ([d][r] + bT).
// grid (16 d-tiles, 16 b); block 256 (thread = one d).
// ---------------------------------------------------------------------------
__global__ __launch_bounds__(256) void kernelBfin(
    const float* __restrict__ qpart, float* __restrict__ bases,
    float* __restrict__ bT,
    const float* __restrict__ CtC, float* __restrict__ BtBadd)
{
  __shared__ __align__(16) float sm[256 * 20 + 4 * 272];
  const int tid = threadIdx.x;
  const int dt = blockIdx.x, b = blockIdx.y;
  const int d = dt * 256 + tid;
  float acc[16];
#pragma unroll
  for (int r = 0; r < 16; ++r) acc[r] = 0.f;
#pragma unroll
  for (int ns = 0; ns < 4; ++ns) {
    const float* __restrict__ qp = qpart + (((size_t)(ns * 16 + b)) * 4096 + d) * 16;
#pragma unroll
    for (int q = 0; q < 4; ++q) {
      float4 v = *(const float4*)(qp + q * 4);
      acc[q * 4 + 0] += v.x; acc[q * 4 + 1] += v.y; acc[q * 4 + 2] += v.z; acc[q * 4 + 3] += v.w;
    }
  }
  float* __restrict__ brow = bases + ((size_t)(b * 4096 + d)) * 16;
  float bv[16];
#pragma unroll
  for (int r = 0; r < 16; ++r) bv[r] = brow[r];
  const float* __restrict__ ctc = CtC + b * 256;
  float den[16];
#pragma unroll
  for (int r = 0; r < 16; ++r) den[r] = 0.f;
#pragma unroll
  for (int s2 = 0; s2 < 16; ++s2) {
    const float bs = bv[s2];
#pragma unroll
    for (int r = 0; r < 16; ++r) den[r] = fmaf(bs, ctc[s2 * 16 + r], den[r]);
  }
  float* __restrict__ btr = bT + ((size_t)(b * 16)) * 4096 + d;
#pragma unroll
  for (int r = 0; r < 16; ++r) {
    float bn = bv[r] * acc[r] / (den[r] + EPS);
    brow[r] = bn;
    btr[(size_t)r * 4096] = bn;   // coalesced per-r store into bT
    sm[tid * 20 + r] = bn;
  }
  __syncthreads();
  const int rq = tid & 3;
  const int s = (tid >> 2) & 15;
  const int g = tid >> 6;
  float a0 = 0.f, a1 = 0.f, a2 = 0.f, a3 = 0.f;
#pragma unroll 4
  for (int l = g * 64; l < g * 64 + 64; ++l) {
    float4 bq = *(const float4*)(&sm[l * 20 + rq * 4]);
    float cs = sm[l * 20 + s];
    a0 = fmaf(cs, bq.x, a0);
    a1 = fmaf(cs, bq.y, a1);
    a2 = fmaf(cs, bq.z, a2);
    a3 = fmaf(cs, bq.w, a3);
  }
  float* part = sm + 5120;
  *(float4*)(&part[g * 272 + s * 16 + rq * 4]) = make_float4(a0, a1, a2, a3);
  __syncthreads();
  float v = part[0 * 272 + tid] + part[1 * 272 + tid] + part[2 * 272 + tid] + part[3 * 272 + tid];
  atomicAdd(BtBadd + b * 256 + tid, v);
}

// ---------------------------------------------------------------------------
// Output: out[b,n,d] = sum_r bases[b,d,r]*coef[b,n,r]
// grid (4 d-tiles, 16 n-slices, 16 b); thread owns 4 d (float4 stores).
// ---------------------------------------------------------------------------
__global__ __launch_bounds__(256) void kernelOut(
    const float* __restrict__ bases, const float* __restrict__ coef,
    float* __restrict__ out)
{
  const int tid = threadIdx.x;
  const int dt = blockIdx.x, ns = blockIdx.y, b = blockIdx.z;
  const int d0 = dt * 1024 + tid * 4;
  float bv[4][16];
#pragma unroll
  for (int k = 0; k < 4; ++k) {
    const float* __restrict__ brow = bases + ((size_t)(b * 4096 + d0 + k)) * 16;
#pragma unroll
    for (int r = 0; r < 16; ++r) bv[k][r] = brow[r];
  }
  const float* __restrict__ cp = coef + ((size_t)(b * 512 + ns * 32)) * 16;
  float* __restrict__ op = out + ((size_t)(b * 512 + ns * 32)) * 4096 + d0;
#pragma unroll 4
  for (int n = 0; n < 32; ++n) {
    const float* __restrict__ crow = cp + n * 16;
    float v[4];
#pragma unroll
    for (int k = 0; k < 4; ++k) {
      float s = 0.f;
#pragma unroll
      for (int r = 0; r < 16; ++r) s = fmaf(bv[k][r], crow[r], s);
      v[k] = s;
    }
    *(float4*)(op + (size_t)n * 4096) = make_float4(v[0], v[1], v[2], v[3]);
  }
}

// ---------------------------------------------------------------------------
extern "C" void kernel_launch(void* const* d_in, const int* in_sizes, int n_in,
                              void* d_out, int out_size, void* d_ws, size_t ws_size,
                              hipStream_t stream) {
  const float* x = (const float*)d_in[0];         // 16*512*4096
  const float* bases_in = (const float*)d_in[1];  // 16*4096*16
  float* out = (float*)d_out;
  float* ws = (float*)d_ws;

  float* bases = ws;               // 1,048,576 floats  [b][d][r]
  float* coef  = bases + 1048576;  // 131,072
  float* Ppart = coef + 131072;    // 262,144 (2 d-half partials)
  float* btb0  = Ppart + 262144;   // 4,096
  float* btb1  = btb0 + 4096;      // 4,096
  float* ctc   = btb1 + 4096;      // 4,096
  float* bT    = ctc + 4096;       // 1,048,576 floats  [b][r][d]
  float* qpart = bT + 1048576;     // 4*16*4096*16 = 4,194,304
  float* btb[2] = {btb0, btb1};

  hipMemsetAsync(btb0, 0, 4096 * sizeof(float), stream);
  hipMemcpyAsync(bases, bases_in, 1048576 * sizeof(float),
                 hipMemcpyDeviceToDevice, stream);
  kernelT<<<dim3(16, 16), 256, 0, stream>>>(bases_in, bT);

  // init: Ppart = X^T B0 (+ctc zero), coef = softmax(100*P); BtB0 = gram(B0)
  kernelA<<<dim3(32, 16, 2), 256, 0, stream>>>(x, bT, Ppart, ctc);
  kernelSM<<<32, 256, 0, stream>>>(Ppart, coef);
  kernelGram<<<dim3(16, 16), 256, 0, stream>>>(bases, btb0, 4096);

  for (int t = 0; t < 7; ++t) {
    if (t > 0) kernelA<<<dim3(32, 16, 2), 256, 0, stream>>>(x, bT, Ppart, ctc);
    kernelCU<<<32, 256, 0, stream>>>(coef, Ppart, btb[t & 1], btb[(t + 1) & 1], ctc);
    kernelBacc<<<dim3(16, 4, 16), 256, 0, stream>>>(x, coef, qpart);
    kernelBfin<<<dim3(16, 16), 256, 0, stream>>>(qpart, bases, bT, ctc, btb[(t + 1) & 1]);
  }

  // final compute_coef with bases_7 / BtB[1], then reconstruct
  kernelA<<<dim3(32, 16, 2), 256, 0, stream>>>(x, bT, Ppart, ctc);
  kernelCU<<<32, 256, 0, stream>>>(coef, Ppart, btb[1], btb[0], ctc);
  kernelOut<<<dim3(4, 16, 16), 256, 0, stream>>>(bases, coef, out);
}